// Round 10
// baseline (412.812 us; speedup 1.0000x reference)
//
#include <hip/hip_runtime.h>
#include <math.h>

// GraphBlock: 2x GATConv(H=2 heads, C=64, concat=False) + BN(train) + GELU + skip + mean-pool
// N=50000, E=1.6M, F_IN=C=64, B=64

__device__ __forceinline__ float lrelu(float x){ return x > 0.f ? x : 0.2f*x; }
__device__ __forceinline__ float gelu_tanh(float x){
  const float k0 = 0.7978845608028654f; // sqrt(2/pi)
  const float k1 = 0.044715f;
  float t = tanhf(k0 * fmaf(k1*x*x, x, x));
  return 0.5f*x*(1.f + t);
}
__device__ __forceinline__ unsigned short f2bf(float f){
  unsigned int u = __float_as_uint(f);
  u = (u + 0x7fffu + ((u >> 16) & 1u)) >> 16;   // RNE
  return (unsigned short)u;
}

// ================= CSR build via 2-level bucket sort =================
// bucket = dst >> 7 (128 nodes per bucket, NB = ceil(N/128) <= 512)
// record = (src << 7) | (dst & 127)  -- src < 2^17, fits u32.

__global__ void p_hist(const int* __restrict__ dst, int* __restrict__ bhist,
                       int E, int NB){
  __shared__ int lh[512];
  for (int i = threadIdx.x; i < NB; i += blockDim.x) lh[i] = 0;
  __syncthreads();
  int stride = gridDim.x * blockDim.x;
  for (int i = blockIdx.x*blockDim.x + threadIdx.x; i < E; i += stride)
    atomicAdd(&lh[dst[i] >> 7], 1);
  __syncthreads();
  for (int i = threadIdx.x; i < NB; i += blockDim.x)
    if (lh[i]) atomicAdd(&bhist[i], lh[i]);
}

__global__ void p_scan(const int* __restrict__ bhist, int* __restrict__ boff,
                       int* __restrict__ bcur, int* __restrict__ ptr,
                       int NB, int N, int E){
  __shared__ int ls[512];
  int t = threadIdx.x;
  int v = (t < NB) ? bhist[t] : 0;
  ls[t] = v; __syncthreads();
  for (int o = 1; o < 512; o <<= 1){
    int y = (t >= o) ? ls[t-o] : 0;
    __syncthreads();
    ls[t] += y;
    __syncthreads();
  }
  int ex = ls[t] - v;
  if (t < NB){ boff[t] = ex; bcur[t] = ex; }
  if (t == 0){ boff[NB] = E; ptr[N] = E; }
}

#define BIN_CHUNK 8192
__global__ void p_bin(const int* __restrict__ src, const int* __restrict__ dst,
                      int* __restrict__ bcur, unsigned int* __restrict__ recs,
                      int E, int NB){
  __shared__ int lh[512];     // local hist, then local cursor
  __shared__ int lbase[512];  // claimed global base per bucket
  int c0 = blockIdx.x * BIN_CHUNK;
  int cnt = min(BIN_CHUNK, E - c0);
  if (cnt <= 0) return;
  int t = threadIdx.x;
  for (int i = t; i < NB; i += blockDim.x) lh[i] = 0;
  __syncthreads();
  for (int i = t; i < cnt; i += blockDim.x)
    atomicAdd(&lh[dst[c0+i] >> 7], 1);
  __syncthreads();
  for (int i = t; i < NB; i += blockDim.x){
    int c = lh[i];
    lbase[i] = (c > 0) ? atomicAdd(&bcur[i], c) : 0;
    lh[i] = 0;   // reuse as local cursor
  }
  __syncthreads();
  for (int i = t; i < cnt; i += blockDim.x){
    int d = dst[c0+i];
    int b = d >> 7;
    int p = atomicAdd(&lh[b], 1);
    recs[lbase[b] + p] = ((unsigned int)src[c0+i] << 7) | (unsigned int)(d & 127);
  }
}

// one block per bucket: counting-sort 128 local nodes; block exclusively owns
// its [r0,r1) window of srcs -> no cross-block line sharing (write amp ~1).
__global__ void p_csr(const unsigned int* __restrict__ recs, const int* __restrict__ boff,
                      int* __restrict__ ptr, int* __restrict__ srcs, int N){
  int b = blockIdx.x;
  int r0 = boff[b], r1 = boff[b+1];
  __shared__ int lh[128];
  int t = threadIdx.x;    // 256 threads
  if (t < 128) lh[t] = 0;
  __syncthreads();
  for (int i = r0 + t; i < r1; i += 256)
    atomicAdd(&lh[recs[i] & 127u], 1);
  __syncthreads();
  int mycnt = (t < 128) ? lh[t] : 0;
  for (int o = 1; o < 128; o <<= 1){
    int y = (t < 128 && t >= o) ? lh[t-o] : 0;
    __syncthreads();
    if (t < 128) lh[t] += y;
    __syncthreads();
  }
  if (t < 128){
    int excl = lh[t] - mycnt;
    int node = b*128 + t;
    if (node < N) ptr[node] = r0 + excl;
    lh[t] = excl;          // reuse as scatter cursor
  }
  __syncthreads();
  for (int i = r0 + t; i < r1; i += 256){
    unsigned int rec = recs[i];
    int j = rec & 127u;
    int p = atomicAdd(&lh[j], 1);
    srcs[r0 + p] = (int)(rec >> 7);
  }
}

// ---- Fused GEMM: wave = 64-col panel of W in VGPRs (asm-pinned).
// Empirical series: VGPR=72 + panel resident (R5, bounds(192,2), 2-row) = 63us;
// VGPR=40 demoted (R4/R7/R8) = 83-89us; VGPR=64 spilled (R6, bounds(192,4)) =
// 90us; LDS panel (R9) = 108us. This round: R6's 4-row ILP body at
// __launch_bounds__(192,3) -> VGPR cap 170 (no spill), 4 blocks/CU (2x R5).
// NP=3: [W1 h0 | W1 h1 | skipW], NP=2: W2. H stored bf16 for k_agg's gather.
template<int NP>
__global__ void __launch_bounds__(192, 3)
k_gemm(const float* __restrict__ X, const float* __restrict__ Wm,
       const float* __restrict__ Wsk, const float* __restrict__ att_s,
       const float* __restrict__ att_d, unsigned short* __restrict__ Hout,
       float* __restrict__ skv, float* __restrict__ a_s,
       float* __restrict__ a_d, int N){
  int lane = threadIdx.x & 63;
  int p = threadIdx.x >> 6;      // panel id (wave-uniform)
  float w[64];
  const float* wb; int stride;
  if (p < 2){ wb = Wm + p*64 + lane; stride = 128; }
  else      { wb = Wsk + lane;       stride = 64;  }
  #pragma unroll
  for (int k=0;k<64;k++) w[k] = wb[(size_t)k*stride];
  #pragma unroll
  for (int k=0;k<64;k++) asm volatile("" : "+v"(w[k]));  // pin in VGPRs
  float asv = 0.f, adv = 0.f;
  if (p < 2){ asv = att_s[p*64+lane]; adv = att_d[p*64+lane]; }

  int r0 = blockIdx.x * 32;
  for (int rr = 0; rr < 32; rr += 4){
    int r = r0 + rr;
    if (r >= N) break;
    int rc[4];
    #pragma unroll
    for (int q=0;q<4;q++) rc[q] = (r+q < N) ? r+q : r;
    const float4* xp0 = (const float4*)(X + (size_t)rc[0]*64);
    const float4* xp1 = (const float4*)(X + (size_t)rc[1]*64);
    const float4* xp2 = (const float4*)(X + (size_t)rc[2]*64);
    const float4* xp3 = (const float4*)(X + (size_t)rc[3]*64);
    float acc[4] = {0.f, 0.f, 0.f, 0.f};
    #pragma unroll
    for (int k4=0;k4<16;k4++){
      float4 u0 = xp0[k4];
      float4 u1 = xp1[k4];
      float4 u2 = xp2[k4];
      float4 u3 = xp3[k4];
      acc[0] = fmaf(u0.x, w[4*k4+0], acc[0]);
      acc[0] = fmaf(u0.y, w[4*k4+1], acc[0]);
      acc[0] = fmaf(u0.z, w[4*k4+2], acc[0]);
      acc[0] = fmaf(u0.w, w[4*k4+3], acc[0]);
      acc[1] = fmaf(u1.x, w[4*k4+0], acc[1]);
      acc[1] = fmaf(u1.y, w[4*k4+1], acc[1]);
      acc[1] = fmaf(u1.z, w[4*k4+2], acc[1]);
      acc[1] = fmaf(u1.w, w[4*k4+3], acc[1]);
      acc[2] = fmaf(u2.x, w[4*k4+0], acc[2]);
      acc[2] = fmaf(u2.y, w[4*k4+1], acc[2]);
      acc[2] = fmaf(u2.z, w[4*k4+2], acc[2]);
      acc[2] = fmaf(u2.w, w[4*k4+3], acc[2]);
      acc[3] = fmaf(u3.x, w[4*k4+0], acc[3]);
      acc[3] = fmaf(u3.y, w[4*k4+1], acc[3]);
      acc[3] = fmaf(u3.z, w[4*k4+2], acc[3]);
      acc[3] = fmaf(u3.w, w[4*k4+3], acc[3]);
    }
    #pragma unroll
    for (int q=0;q<4;q++){
      if (r+q >= N) break;
      float a = acc[q];
      if (p < 2){
        Hout[(size_t)(r+q)*128 + p*64 + lane] = f2bf(a);
        float ps = a*asv, pd = a*adv;
        #pragma unroll
        for (int o=32;o>0;o>>=1){ ps += __shfl_xor(ps,o); pd += __shfl_xor(pd,o); }
        if (lane==0){ a_s[2*(r+q)+p] = ps; a_d[2*(r+q)+p] = pd; }
      } else {
        skv[(size_t)(r+q)*64 + lane] = a;
      }
    }
  }
}

// ---- GAT aggregation: one wave per node, single pass (no max-shift).
// bf16-packed H gather: one dword/lane per edge (2 channels of this lane's head).
__global__ void k_agg(const unsigned short* __restrict__ Hp, const float* __restrict__ a_s,
                      const float* __restrict__ a_d, const int* __restrict__ ptr,
                      const int* __restrict__ srcs, const float* __restrict__ bias,
                      float* __restrict__ out, int N){
  __shared__ float4 cbuf[256];           // 4 waves * 64 entries
  int tid = threadIdx.x;
  int wid = (blockIdx.x*blockDim.x + tid) >> 6;
  int lane = tid & 63;
  float4* mybuf = cbuf + (tid >> 6)*64;
  if (wid >= N) return;
  int n = wid;
  const unsigned int* HP = (const unsigned int*)Hp;   // [N][64] dwords
  const float2* AS2 = (const float2*)a_s;
  float2 adv = ((const float2*)a_d)[n];
  float2 asv = AS2[n];
  int e0 = ptr[n], e1 = ptr[n+1];
  // self-loop
  float w0 = __expf(lrelu(asv.x + adv.x));
  float w1 = __expf(lrelu(asv.y + adv.y));
  unsigned int hw = HP[(size_t)n*64 + lane];
  float wsel = (lane < 32) ? w0 : w1;
  float acc0 = __uint_as_float(hw << 16) * wsel;
  float acc1 = __uint_as_float(hw & 0xffff0000u) * wsel;
  float d0 = 0.f, d1 = 0.f;
  for (int base = e0; base < e1; base += 64){
    int i = base + lane;
    float e_0 = 0.f, e_1 = 0.f; int sv = 0;
    if (i < e1){
      sv = srcs[i];
      float2 av = AS2[sv];
      e_0 = __expf(lrelu(av.x + adv.x));
      e_1 = __expf(lrelu(av.y + adv.y));
    }
    d0 += e_0; d1 += e_1;
    float4 pk; pk.x = __int_as_float(sv); pk.y = e_0; pk.z = e_1; pk.w = 0.f;
    mybuf[lane] = pk;
    int cnt = min(64, e1 - base);
    #pragma unroll 8
    for (int j = 0; j < cnt; j++){
      float4 c = mybuf[j];                        // wave-uniform broadcast read
      int sj = __float_as_int(c.x);
      unsigned int hj = HP[(size_t)sj*64 + lane];
      float wss = (lane < 32) ? c.y : c.z;
      acc0 = fmaf(__uint_as_float(hj << 16),        wss, acc0);
      acc1 = fmaf(__uint_as_float(hj & 0xffff0000u), wss, acc1);
    }
  }
  #pragma unroll
  for (int o=32;o>0;o>>=1){ d0 += __shfl_xor(d0,o); d1 += __shfl_xor(d1,o); }
  d0 += w0; d1 += w1;
  float dsel = (lane < 32) ? d0 : d1;
  acc0 /= dsel; acc1 /= dsel;
  // head mean: lane l (<32) pairs with lane l+32 (head 1, same channels)
  float o0 = 0.5f*(acc0 + __shfl_xor(acc0, 32));
  float o1 = 0.5f*(acc1 + __shfl_xor(acc1, 32));
  if (lane < 32){
    float2 res; res.x = o0 + bias[2*lane]; res.y = o1 + bias[2*lane+1];
    ((float2*)out)[(size_t)n*32 + lane] = res;
  }
}

// ---- BN stats: per-channel sum / sumsq ----
__global__ void k_bnstats(const float* __restrict__ X, float* __restrict__ part, int N){
  int t = threadIdx.x; int c = t & 63; int sub = t >> 6;
  float s = 0.f, s2 = 0.f;
  for (int r = blockIdx.x*4 + sub; r < N; r += gridDim.x*4){
    float v = X[(size_t)r*64 + c];
    s += v; s2 = fmaf(v, v, s2);
  }
  __shared__ float ls[256], lq[256];
  ls[t] = s; lq[t] = s2; __syncthreads();
  if (t < 64){
    s  = ls[t] + ls[t+64] + ls[t+128] + ls[t+192];
    s2 = lq[t] + lq[t+64] + lq[t+128] + lq[t+192];
    atomicAdd(&part[t], s);
    atomicAdd(&part[64+t], s2);
  }
}

__global__ void k_bnfinal(const float* __restrict__ part, const float* __restrict__ gamma,
                          const float* __restrict__ beta, float* __restrict__ bnb, int N){
  int c = threadIdx.x;
  float mu  = part[c] / (float)N;
  float var = part[64+c] / (float)N - mu*mu;
  var = fmaxf(var, 0.f);
  float sc = gamma[c] * rsqrtf(var + 1e-5f);
  bnb[c] = sc;
  bnb[64+c] = beta[c] - mu*sc;
}

// ---- hmid = gelu(bn(g1) + skip + skipb) ----
__global__ void k_fuse1(const float* __restrict__ g1, const float* __restrict__ bn,
                        const float* __restrict__ skip, const float* __restrict__ skipb,
                        float* __restrict__ hmid, int total){
  int i = blockIdx.x*blockDim.x + threadIdx.x;
  if (i < total){
    int c = i & 63;
    float v = fmaf(g1[i], bn[c], bn[64+c]) + skip[i] + skipb[c];
    hmid[i] = gelu_tanh(v);
  }
}

// ---- final: gelu(bn(g2)+hmid), pooled sums per batch (batch_index sorted) ----
__global__ void k_fusepool(const float* __restrict__ g2, const float* __restrict__ bn,
                           const float* __restrict__ hmid, const int* __restrict__ batch,
                           float* __restrict__ pool, float* __restrict__ cnt, int N){
  int t = threadIdx.x; int c = t & 63; int sub = t >> 6;
  int r0 = blockIdx.x*64;
  float scale = bn[c], shift = bn[64+c];
  float acc = 0.f, ca = 0.f; int curb = -1;
  for (int r = r0 + sub; r < N && r < r0 + 64; r += 4){
    int b = batch[r];
    if (b != curb){
      if (curb >= 0){
        atomicAdd(&pool[curb*64 + c], acc);
        if (c == 0) atomicAdd(&cnt[curb], ca);
      }
      acc = 0.f; ca = 0.f; curb = b;
    }
    float v = gelu_tanh(fmaf(g2[(size_t)r*64 + c], scale, shift) + hmid[(size_t)r*64 + c]);
    acc += v; ca += 1.f;
  }
  if (curb >= 0){
    atomicAdd(&pool[curb*64 + c], acc);
    if (c == 0) atomicAdd(&cnt[curb], ca);
  }
}

__global__ void k_out(const float* __restrict__ pool, const float* __restrict__ cnt,
                      float* __restrict__ out, int M){
  int i = blockIdx.x*blockDim.x + threadIdx.x;
  if (i < M) out[i] = pool[i] / fmaxf(cnt[i>>6], 1.f);
}

extern "C" void kernel_launch(void* const* d_in, const int* in_sizes, int n_in,
                              void* d_out, int out_size, void* d_ws, size_t ws_size,
                              hipStream_t stream) {
  const float* x     = (const float*)d_in[0];
  const int*   ei    = (const int*)  d_in[1];
  const int*   batch = (const int*)  d_in[2];
  const float* W1    = (const float*)d_in[3];
  const float* as1   = (const float*)d_in[4];
  const float* ad1   = (const float*)d_in[5];
  const float* b1    = (const float*)d_in[6];
  const float* skW   = (const float*)d_in[7];
  const float* skb   = (const float*)d_in[8];
  const float* gm1   = (const float*)d_in[9];
  const float* bt1   = (const float*)d_in[10];
  const float* W2    = (const float*)d_in[11];
  const float* as2   = (const float*)d_in[12];
  const float* ad2   = (const float*)d_in[13];
  const float* b2    = (const float*)d_in[14];
  const float* gm2   = (const float*)d_in[15];
  const float* bt2   = (const float*)d_in[16];

  int N = in_sizes[2];
  int E = in_sizes[1] / 2;
  const int* esrc = ei;
  const int* edst = ei + E;
  int NB = (N + 127) >> 7;          // 128-node buckets

  char* wp = (char*)d_ws;
  size_t off = 0;
  auto alloc = [&](size_t bytes)->void*{
    off = (off + 255) & ~(size_t)255;
    void* p = wp + off;
    off += bytes;
    return p;
  };
  int*   ptr   = (int*)  alloc((size_t)(N+1)*4);
  int*   srcs  = (int*)  alloc((size_t)E*4);
  unsigned int* recs = (unsigned int*)alloc((size_t)E*4);
  int*   bhist = (int*)  alloc(512*4);
  int*   boff  = (int*)  alloc(520*4);
  int*   bcur  = (int*)  alloc(512*4);
  unsigned short* hpack = (unsigned short*)alloc((size_t)N*128*2);  // bf16 H
  float* a_s  = (float*)alloc((size_t)N*2*4);
  float* a_d  = (float*)alloc((size_t)N*2*4);
  float* gout = (float*)alloc((size_t)N*64*4);   // GAT raw output (both layers)
  float* skv  = (float*)alloc((size_t)N*64*4);   // x @ skipW
  float* hmid = (float*)alloc((size_t)N*64*4);   // layer-1 final output
  float* zz   = (float*)alloc((size_t)(128+128+4096+64)*4); // zero zone
  float* part1 = zz;
  float* part2 = zz + 128;
  float* pool  = zz + 256;
  float* cnt   = zz + 256 + 4096;
  float* bnb1 = (float*)alloc(128*4);
  float* bnb2 = (float*)alloc(128*4);

  hipMemsetAsync(bhist, 0, 512*4, stream);
  hipMemsetAsync(zz, 0, (size_t)(128+128+4096+64)*4, stream);

  int gg = (N + 31) / 32;

  // CSR build (bucket sort)
  p_hist<<<512, 256, 0, stream>>>(edst, bhist, E, NB);
  p_scan<<<1, 512, 0, stream>>>(bhist, boff, bcur, ptr, NB, N, E);
  p_bin<<<(E + BIN_CHUNK - 1)/BIN_CHUNK, 256, 0, stream>>>(esrc, edst, bcur, recs, E, NB);
  p_csr<<<NB, 256, 0, stream>>>(recs, boff, ptr, srcs, N);

  // layer 1 (W1 + skip + att fused)
  k_gemm<3><<<gg, 192, 0, stream>>>(x, W1, skW, as1, ad1, hpack, skv, a_s, a_d, N);
  k_agg<<<(N+3)/4, 256, 0, stream>>>(hpack, a_s, a_d, ptr, srcs, b1, gout, N);
  k_bnstats<<<256, 256, 0, stream>>>(gout, part1, N);
  k_bnfinal<<<1, 64, 0, stream>>>(part1, gm1, bt1, bnb1, N);
  k_fuse1<<<(N*64 + 255)/256, 256, 0, stream>>>(gout, bnb1, skv, skb, hmid, N*64);

  // layer 2
  k_gemm<2><<<gg, 128, 0, stream>>>(hmid, W2, nullptr, as2, ad2, hpack, nullptr, a_s, a_d, N);
  k_agg<<<(N+3)/4, 256, 0, stream>>>(hpack, a_s, a_d, ptr, srcs, b2, gout, N);
  k_bnstats<<<256, 256, 0, stream>>>(gout, part2, N);
  k_bnfinal<<<1, 64, 0, stream>>>(part2, gm2, bt2, bnb2, N);

  // fuse + pool
  k_fusepool<<<(N+63)/64, 256, 0, stream>>>(gout, bnb2, hmid, batch, pool, cnt, N);
  k_out<<<(out_size + 255)/256, 256, 0, stream>>>(pool, cnt, (float*)d_out, out_size);
}

// Round 11
// 298.166 us; speedup vs baseline: 1.3845x; 1.3845x over previous
//
#include <hip/hip_runtime.h>
#include <math.h>

// GraphBlock: 2x GATConv(H=2 heads, C=64, concat=False) + BN(train) + GELU + skip + mean-pool
// N=50000, E=1.6M, F_IN=C=64, B=64

__device__ __forceinline__ float lrelu(float x){ return x > 0.f ? x : 0.2f*x; }
__device__ __forceinline__ float gelu_tanh(float x){
  const float k0 = 0.7978845608028654f; // sqrt(2/pi)
  const float k1 = 0.044715f;
  float t = tanhf(k0 * fmaf(k1*x*x, x, x));
  return 0.5f*x*(1.f + t);
}
__device__ __forceinline__ unsigned short f2bf(float f){
  unsigned int u = __float_as_uint(f);
  u = (u + 0x7fffu + ((u >> 16) & 1u)) >> 16;   // RNE
  return (unsigned short)u;
}

typedef __attribute__((ext_vector_type(8))) short bf16x8;
typedef __attribute__((ext_vector_type(4))) float f32x4;

// ================= CSR build via 2-level bucket sort =================
__global__ void p_hist(const int* __restrict__ dst, int* __restrict__ bhist,
                       int E, int NB){
  __shared__ int lh[512];
  for (int i = threadIdx.x; i < NB; i += blockDim.x) lh[i] = 0;
  __syncthreads();
  int stride = gridDim.x * blockDim.x;
  for (int i = blockIdx.x*blockDim.x + threadIdx.x; i < E; i += stride)
    atomicAdd(&lh[dst[i] >> 7], 1);
  __syncthreads();
  for (int i = threadIdx.x; i < NB; i += blockDim.x)
    if (lh[i]) atomicAdd(&bhist[i], lh[i]);
}

__global__ void p_scan(const int* __restrict__ bhist, int* __restrict__ boff,
                       int* __restrict__ bcur, int* __restrict__ ptr,
                       int NB, int N, int E){
  __shared__ int ls[512];
  int t = threadIdx.x;
  int v = (t < NB) ? bhist[t] : 0;
  ls[t] = v; __syncthreads();
  for (int o = 1; o < 512; o <<= 1){
    int y = (t >= o) ? ls[t-o] : 0;
    __syncthreads();
    ls[t] += y;
    __syncthreads();
  }
  int ex = ls[t] - v;
  if (t < NB){ boff[t] = ex; bcur[t] = ex; }
  if (t == 0){ boff[NB] = E; ptr[N] = E; }
}

#define BIN_CHUNK 8192
__global__ void p_bin(const int* __restrict__ src, const int* __restrict__ dst,
                      int* __restrict__ bcur, unsigned int* __restrict__ recs,
                      int E, int NB){
  __shared__ int lh[512];
  __shared__ int lbase[512];
  int c0 = blockIdx.x * BIN_CHUNK;
  int cnt = min(BIN_CHUNK, E - c0);
  if (cnt <= 0) return;
  int t = threadIdx.x;
  for (int i = t; i < NB; i += blockDim.x) lh[i] = 0;
  __syncthreads();
  for (int i = t; i < cnt; i += blockDim.x)
    atomicAdd(&lh[dst[c0+i] >> 7], 1);
  __syncthreads();
  for (int i = t; i < NB; i += blockDim.x){
    int c = lh[i];
    lbase[i] = (c > 0) ? atomicAdd(&bcur[i], c) : 0;
    lh[i] = 0;
  }
  __syncthreads();
  for (int i = t; i < cnt; i += blockDim.x){
    int d = dst[c0+i];
    int b = d >> 7;
    int p = atomicAdd(&lh[b], 1);
    recs[lbase[b] + p] = ((unsigned int)src[c0+i] << 7) | (unsigned int)(d & 127);
  }
}

__global__ void p_csr(const unsigned int* __restrict__ recs, const int* __restrict__ boff,
                      int* __restrict__ ptr, int* __restrict__ srcs, int N){
  int b = blockIdx.x;
  int r0 = boff[b], r1 = boff[b+1];
  __shared__ int lh[128];
  int t = threadIdx.x;
  if (t < 128) lh[t] = 0;
  __syncthreads();
  for (int i = r0 + t; i < r1; i += 256)
    atomicAdd(&lh[recs[i] & 127u], 1);
  __syncthreads();
  int mycnt = (t < 128) ? lh[t] : 0;
  for (int o = 1; o < 128; o <<= 1){
    int y = (t < 128 && t >= o) ? lh[t-o] : 0;
    __syncthreads();
    if (t < 128) lh[t] += y;
    __syncthreads();
  }
  if (t < 128){
    int excl = lh[t] - mycnt;
    int node = b*128 + t;
    if (node < N) ptr[node] = r0 + excl;
    lh[t] = excl;
  }
  __syncthreads();
  for (int i = r0 + t; i < r1; i += 256){
    unsigned int rec = recs[i];
    int j = rec & 127u;
    int p = atomicAdd(&lh[j], 1);
    srcs[r0 + p] = (int)(rec >> 7);
  }
}

// ---- MFMA GEMM (R10 post-mortem: fp32-FMA formulation is structurally
// allocator-bound, 63-108us across 6 variants). Y[N x NG*64] = X[N x 64] @ W.
// mfma_f32_16x16x32_bf16, K=64 -> 2 mfma per 16x16 tile. W staged to LDS as
// pre-swizzled bf16 B-frags; each wave computes 2 strips of 16 rows over ALL
// col tiles (dots complete in-wave). Fragment layouts: C/D col=l&15,
// row=(l>>4)*4+reg [m89]; A/B elem e -> k=(e>>2)*16+(l>>4)*4+(e&3) (derived
// from verified 32x32 crow pattern + tr_b16 mapping). NG=3 adds skipW tiles.
template<int NG>
__global__ void k_gemm(const float* __restrict__ X, const float* __restrict__ Wm,
                       const float* __restrict__ Wsk, const float* __restrict__ att_s,
                       const float* __restrict__ att_d, unsigned short* __restrict__ Hout,
                       float* __restrict__ skv, float* __restrict__ a_s,
                       float* __restrict__ a_d, int N){
  constexpr int NT = NG*4;                    // 16-col tiles
  __shared__ unsigned short Bl[NT*2*64*8];    // [tile][khalf][lane][8] bf16
  int t = threadIdx.x;
  // stage W -> swizzled bf16 frags (coalesced fp32 reads, scattered 2B LDS writes)
  const int TOT = 64 * NG * 64;               // k * cols
  for (int e = t; e < TOT; e += 256){
    int k = e / (NG*64), c = e % (NG*64);
    float w = (c < 128) ? Wm[(size_t)k*128 + c] : Wsk[(size_t)k*64 + (c-128)];
    int ct = c >> 4;
    int h = k >> 5, kk = k & 31;
    int e2 = ((kk >> 4) << 2) | (kk & 3);
    int l  = (c & 15) | (((kk >> 2) & 3) << 4);
    Bl[(((ct*2 + h)*64) + l)*8 + e2] = f2bf(w);
  }
  __syncthreads();

  int lane = t & 63, wav = t >> 6;
  int m = lane & 15, g = lane >> 4;           // out-col-in-tile, lane group
  // attention coefficient per (tile, lane): col = ct*16 + m (head-major flat)
  float asv[8], adv[8];
  #pragma unroll
  for (int ct = 0; ct < 8; ct++){ asv[ct] = att_s[ct*16 + m]; adv[ct] = att_d[ct*16 + m]; }

  #pragma unroll
  for (int it = 0; it < 2; it++){
    int rbase = blockIdx.x*128 + it*64 + wav*16;
    if (rbase >= N) break;
    // A frags: row = rbase + m, k = (e>>2)*16 + g*4 + (e&3)  (+32 for frag1)
    int r = min(rbase + m, N-1);
    const float* xr = X + (size_t)r*64;
    float4 u0 = *(const float4*)(xr + g*4);
    float4 u1 = *(const float4*)(xr + 16 + g*4);
    float4 u2 = *(const float4*)(xr + 32 + g*4);
    float4 u3 = *(const float4*)(xr + 48 + g*4);
    bf16x8 a0, a1;
    a0[0]=(short)f2bf(u0.x); a0[1]=(short)f2bf(u0.y); a0[2]=(short)f2bf(u0.z); a0[3]=(short)f2bf(u0.w);
    a0[4]=(short)f2bf(u1.x); a0[5]=(short)f2bf(u1.y); a0[6]=(short)f2bf(u1.z); a0[7]=(short)f2bf(u1.w);
    a1[0]=(short)f2bf(u2.x); a1[1]=(short)f2bf(u2.y); a1[2]=(short)f2bf(u2.z); a1[3]=(short)f2bf(u2.w);
    a1[4]=(short)f2bf(u3.x); a1[5]=(short)f2bf(u3.y); a1[6]=(short)f2bf(u3.z); a1[7]=(short)f2bf(u3.w);

    f32x4 acc[NT];
    #pragma unroll
    for (int ct = 0; ct < NT; ct++) acc[ct] = (f32x4){0.f,0.f,0.f,0.f};
    #pragma unroll
    for (int ct = 0; ct < NT; ct++){
      bf16x8 b0 = *(const bf16x8*)&Bl[((ct*2+0)*64 + lane)*8];
      bf16x8 b1 = *(const bf16x8*)&Bl[((ct*2+1)*64 + lane)*8];
      acc[ct] = __builtin_amdgcn_mfma_f32_16x16x32_bf16(a0, b0, acc[ct], 0, 0, 0);
      acc[ct] = __builtin_amdgcn_mfma_f32_16x16x32_bf16(a1, b1, acc[ct], 0, 0, 0);
    }

    // ---- dots (tiles 0..7 = the two heads) ----
    float ds0[4]={0,0,0,0}, dd0[4]={0,0,0,0}, ds1[4]={0,0,0,0}, dd1[4]={0,0,0,0};
    #pragma unroll
    for (int ct = 0; ct < 8; ct++){
      #pragma unroll
      for (int q = 0; q < 4; q++){
        float v = acc[ct][q];
        if (ct < 4){ ds0[q] = fmaf(v, asv[ct], ds0[q]); dd0[q] = fmaf(v, adv[ct], dd0[q]); }
        else       { ds1[q] = fmaf(v, asv[ct], ds1[q]); dd1[q] = fmaf(v, adv[ct], dd1[q]); }
      }
    }
    #pragma unroll
    for (int off = 1; off < 16; off <<= 1){
      #pragma unroll
      for (int q = 0; q < 4; q++){
        ds0[q] += __shfl_xor(ds0[q], off); dd0[q] += __shfl_xor(dd0[q], off);
        ds1[q] += __shfl_xor(ds1[q], off); dd1[q] += __shfl_xor(dd1[q], off);
      }
    }
    if (m == 0){
      #pragma unroll
      for (int q = 0; q < 4; q++){
        int rr = rbase + g*4 + q;
        if (rr < N){
          float2 s2; s2.x = ds0[q]; s2.y = ds1[q]; ((float2*)a_s)[rr] = s2;
          float2 d2; d2.x = dd0[q]; d2.y = dd1[q]; ((float2*)a_d)[rr] = d2;
        }
      }
    }
    // ---- H store (bf16) ----
    #pragma unroll
    for (int ct = 0; ct < 8; ct++){
      #pragma unroll
      for (int q = 0; q < 4; q++){
        int rr = rbase + g*4 + q;
        if (rr < N) Hout[(size_t)rr*128 + ct*16 + m] = f2bf(acc[ct][q]);
      }
    }
    // ---- skip path (fp32) ----
    if (NG >= 3){
      #pragma unroll
      for (int ct = 8; ct < NT; ct++){
        #pragma unroll
        for (int q = 0; q < 4; q++){
          int rr = rbase + g*4 + q;
          if (rr < N) skv[(size_t)rr*64 + (ct-8)*16 + m] = acc[ct][q];
        }
      }
    }
  }
}

// ---- GAT aggregation: one wave per node, single pass (no max-shift).
// bf16-packed H gather: one dword/lane per edge (2 channels of this lane's head).
__global__ void k_agg(const unsigned short* __restrict__ Hp, const float* __restrict__ a_s,
                      const float* __restrict__ a_d, const int* __restrict__ ptr,
                      const int* __restrict__ srcs, const float* __restrict__ bias,
                      float* __restrict__ out, int N){
  __shared__ float4 cbuf[256];           // 4 waves * 64 entries
  int tid = threadIdx.x;
  int wid = (blockIdx.x*blockDim.x + tid) >> 6;
  int lane = tid & 63;
  float4* mybuf = cbuf + (tid >> 6)*64;
  if (wid >= N) return;
  int n = wid;
  const unsigned int* HP = (const unsigned int*)Hp;   // [N][64] dwords
  const float2* AS2 = (const float2*)a_s;
  float2 adv = ((const float2*)a_d)[n];
  float2 asv = AS2[n];
  int e0 = ptr[n], e1 = ptr[n+1];
  float w0 = __expf(lrelu(asv.x + adv.x));
  float w1 = __expf(lrelu(asv.y + adv.y));
  unsigned int hw = HP[(size_t)n*64 + lane];
  float wsel = (lane < 32) ? w0 : w1;
  float acc0 = __uint_as_float(hw << 16) * wsel;
  float acc1 = __uint_as_float(hw & 0xffff0000u) * wsel;
  float d0 = 0.f, d1 = 0.f;
  for (int base = e0; base < e1; base += 64){
    int i = base + lane;
    float e_0 = 0.f, e_1 = 0.f; int sv = 0;
    if (i < e1){
      sv = srcs[i];
      float2 av = AS2[sv];
      e_0 = __expf(lrelu(av.x + adv.x));
      e_1 = __expf(lrelu(av.y + adv.y));
    }
    d0 += e_0; d1 += e_1;
    float4 pk; pk.x = __int_as_float(sv); pk.y = e_0; pk.z = e_1; pk.w = 0.f;
    mybuf[lane] = pk;
    int cnt = min(64, e1 - base);
    #pragma unroll 8
    for (int j = 0; j < cnt; j++){
      float4 c = mybuf[j];                        // wave-uniform broadcast read
      int sj = __float_as_int(c.x);
      unsigned int hj = HP[(size_t)sj*64 + lane];
      float wss = (lane < 32) ? c.y : c.z;
      acc0 = fmaf(__uint_as_float(hj << 16),        wss, acc0);
      acc1 = fmaf(__uint_as_float(hj & 0xffff0000u), wss, acc1);
    }
  }
  #pragma unroll
  for (int o=32;o>0;o>>=1){ d0 += __shfl_xor(d0,o); d1 += __shfl_xor(d1,o); }
  d0 += w0; d1 += w1;
  float dsel = (lane < 32) ? d0 : d1;
  acc0 /= dsel; acc1 /= dsel;
  float o0 = 0.5f*(acc0 + __shfl_xor(acc0, 32));
  float o1 = 0.5f*(acc1 + __shfl_xor(acc1, 32));
  if (lane < 32){
    float2 res; res.x = o0 + bias[2*lane]; res.y = o1 + bias[2*lane+1];
    ((float2*)out)[(size_t)n*32 + lane] = res;
  }
}

// ---- BN stats: per-channel sum / sumsq ----
__global__ void k_bnstats(const float* __restrict__ X, float* __restrict__ part, int N){
  int t = threadIdx.x; int c = t & 63; int sub = t >> 6;
  float s = 0.f, s2 = 0.f;
  for (int r = blockIdx.x*4 + sub; r < N; r += gridDim.x*4){
    float v = X[(size_t)r*64 + c];
    s += v; s2 = fmaf(v, v, s2);
  }
  __shared__ float ls[256], lq[256];
  ls[t] = s; lq[t] = s2; __syncthreads();
  if (t < 64){
    s  = ls[t] + ls[t+64] + ls[t+128] + ls[t+192];
    s2 = lq[t] + lq[t+64] + lq[t+128] + lq[t+192];
    atomicAdd(&part[t], s);
    atomicAdd(&part[64+t], s2);
  }
}

__global__ void k_bnfinal(const float* __restrict__ part, const float* __restrict__ gamma,
                          const float* __restrict__ beta, float* __restrict__ bnb, int N){
  int c = threadIdx.x;
  float mu  = part[c] / (float)N;
  float var = part[64+c] / (float)N - mu*mu;
  var = fmaxf(var, 0.f);
  float sc = gamma[c] * rsqrtf(var + 1e-5f);
  bnb[c] = sc;
  bnb[64+c] = beta[c] - mu*sc;
}

// ---- hmid = gelu(bn(g1) + skip + skipb) ----
__global__ void k_fuse1(const float* __restrict__ g1, const float* __restrict__ bn,
                        const float* __restrict__ skip, const float* __restrict__ skipb,
                        float* __restrict__ hmid, int total){
  int i = blockIdx.x*blockDim.x + threadIdx.x;
  if (i < total){
    int c = i & 63;
    float v = fmaf(g1[i], bn[c], bn[64+c]) + skip[i] + skipb[c];
    hmid[i] = gelu_tanh(v);
  }
}

// ---- final: gelu(bn(g2)+hmid), pooled sums per batch (batch_index sorted) ----
__global__ void k_fusepool(const float* __restrict__ g2, const float* __restrict__ bn,
                           const float* __restrict__ hmid, const int* __restrict__ batch,
                           float* __restrict__ pool, float* __restrict__ cnt, int N){
  int t = threadIdx.x; int c = t & 63; int sub = t >> 6;
  int r0 = blockIdx.x*64;
  float scale = bn[c], shift = bn[64+c];
  float acc = 0.f, ca = 0.f; int curb = -1;
  for (int r = r0 + sub; r < N && r < r0 + 64; r += 4){
    int b = batch[r];
    if (b != curb){
      if (curb >= 0){
        atomicAdd(&pool[curb*64 + c], acc);
        if (c == 0) atomicAdd(&cnt[curb], ca);
      }
      acc = 0.f; ca = 0.f; curb = b;
    }
    float v = gelu_tanh(fmaf(g2[(size_t)r*64 + c], scale, shift) + hmid[(size_t)r*64 + c]);
    acc += v; ca += 1.f;
  }
  if (curb >= 0){
    atomicAdd(&pool[curb*64 + c], acc);
    if (c == 0) atomicAdd(&cnt[curb], ca);
  }
}

__global__ void k_out(const float* __restrict__ pool, const float* __restrict__ cnt,
                      float* __restrict__ out, int M){
  int i = blockIdx.x*blockDim.x + threadIdx.x;
  if (i < M) out[i] = pool[i] / fmaxf(cnt[i>>6], 1.f);
}

extern "C" void kernel_launch(void* const* d_in, const int* in_sizes, int n_in,
                              void* d_out, int out_size, void* d_ws, size_t ws_size,
                              hipStream_t stream) {
  const float* x     = (const float*)d_in[0];
  const int*   ei    = (const int*)  d_in[1];
  const int*   batch = (const int*)  d_in[2];
  const float* W1    = (const float*)d_in[3];
  const float* as1   = (const float*)d_in[4];
  const float* ad1   = (const float*)d_in[5];
  const float* b1    = (const float*)d_in[6];
  const float* skW   = (const float*)d_in[7];
  const float* skb   = (const float*)d_in[8];
  const float* gm1   = (const float*)d_in[9];
  const float* bt1   = (const float*)d_in[10];
  const float* W2    = (const float*)d_in[11];
  const float* as2   = (const float*)d_in[12];
  const float* ad2   = (const float*)d_in[13];
  const float* b2    = (const float*)d_in[14];
  const float* gm2   = (const float*)d_in[15];
  const float* bt2   = (const float*)d_in[16];

  int N = in_sizes[2];
  int E = in_sizes[1] / 2;
  const int* esrc = ei;
  const int* edst = ei + E;
  int NB = (N + 127) >> 7;          // 128-node buckets

  char* wp = (char*)d_ws;
  size_t off = 0;
  auto alloc = [&](size_t bytes)->void*{
    off = (off + 255) & ~(size_t)255;
    void* p = wp + off;
    off += bytes;
    return p;
  };
  int*   ptr   = (int*)  alloc((size_t)(N+1)*4);
  int*   srcs  = (int*)  alloc((size_t)E*4);
  unsigned int* recs = (unsigned int*)alloc((size_t)E*4);
  int*   bhist = (int*)  alloc(512*4);
  int*   boff  = (int*)  alloc(520*4);
  int*   bcur  = (int*)  alloc(512*4);
  unsigned short* hpack = (unsigned short*)alloc((size_t)N*128*2);  // bf16 H
  float* a_s  = (float*)alloc((size_t)N*2*4);
  float* a_d  = (float*)alloc((size_t)N*2*4);
  float* gout = (float*)alloc((size_t)N*64*4);   // GAT raw output (both layers)
  float* skv  = (float*)alloc((size_t)N*64*4);   // x @ skipW
  float* hmid = (float*)alloc((size_t)N*64*4);   // layer-1 final output
  float* zz   = (float*)alloc((size_t)(128+128+4096+64)*4); // zero zone
  float* part1 = zz;
  float* part2 = zz + 128;
  float* pool  = zz + 256;
  float* cnt   = zz + 256 + 4096;
  float* bnb1 = (float*)alloc(128*4);
  float* bnb2 = (float*)alloc(128*4);

  hipMemsetAsync(bhist, 0, 512*4, stream);
  hipMemsetAsync(zz, 0, (size_t)(128+128+4096+64)*4, stream);

  int gg = (N + 127) / 128;

  // CSR build (bucket sort)
  p_hist<<<512, 256, 0, stream>>>(edst, bhist, E, NB);
  p_scan<<<1, 512, 0, stream>>>(bhist, boff, bcur, ptr, NB, N, E);
  p_bin<<<(E + BIN_CHUNK - 1)/BIN_CHUNK, 256, 0, stream>>>(esrc, edst, bcur, recs, E, NB);
  p_csr<<<NB, 256, 0, stream>>>(recs, boff, ptr, srcs, N);

  // layer 1 (W1 + skip + att fused, MFMA)
  k_gemm<3><<<gg, 256, 0, stream>>>(x, W1, skW, as1, ad1, hpack, skv, a_s, a_d, N);
  k_agg<<<(N+3)/4, 256, 0, stream>>>(hpack, a_s, a_d, ptr, srcs, b1, gout, N);
  k_bnstats<<<256, 256, 0, stream>>>(gout, part1, N);
  k_bnfinal<<<1, 64, 0, stream>>>(part1, gm1, bt1, bnb1, N);
  k_fuse1<<<(N*64 + 255)/256, 256, 0, stream>>>(gout, bnb1, skv, skb, hmid, N*64);

  // layer 2
  k_gemm<2><<<gg, 256, 0, stream>>>(hmid, W2, nullptr, as2, ad2, hpack, nullptr, a_s, a_d, N);
  k_agg<<<(N+3)/4, 256, 0, stream>>>(hpack, a_s, a_d, ptr, srcs, b2, gout, N);
  k_bnstats<<<256, 256, 0, stream>>>(gout, part2, N);
  k_bnfinal<<<1, 64, 0, stream>>>(part2, gm2, bt2, bnb2, N);

  // fuse + pool
  k_fusepool<<<(N+63)/64, 256, 0, stream>>>(gout, bnb2, hmid, batch, pool, cnt, N);
  k_out<<<(out_size + 255)/256, 256, 0, stream>>>(pool, cnt, (float*)d_out, out_size);
}

// Round 12
// 286.443 us; speedup vs baseline: 1.4412x; 1.0409x over previous
//
#include <hip/hip_runtime.h>
#include <math.h>

// GraphBlock: 2x GATConv(H=2 heads, C=64, concat=False) + BN(train) + GELU + skip + mean-pool
// N=50000, E=1.6M, F_IN=C=64, B=64

__device__ __forceinline__ float lrelu(float x){ return x > 0.f ? x : 0.2f*x; }
__device__ __forceinline__ float gelu_tanh(float x){
  const float k0 = 0.7978845608028654f; // sqrt(2/pi)
  const float k1 = 0.044715f;
  float t = tanhf(k0 * fmaf(k1*x*x, x, x));
  return 0.5f*x*(1.f + t);
}
__device__ __forceinline__ unsigned short f2bf(float f){
  unsigned int u = __float_as_uint(f);
  u = (u + 0x7fffu + ((u >> 16) & 1u)) >> 16;   // RNE
  return (unsigned short)u;
}

typedef __attribute__((ext_vector_type(8))) short bf16x8;
typedef __attribute__((ext_vector_type(4))) float f32x4;

// ================= CSR build via 2-level bucket sort =================
__global__ void p_hist(const int* __restrict__ dst, int* __restrict__ bhist,
                       int E, int NB){
  __shared__ int lh[512];
  for (int i = threadIdx.x; i < NB; i += blockDim.x) lh[i] = 0;
  __syncthreads();
  int stride = gridDim.x * blockDim.x;
  for (int i = blockIdx.x*blockDim.x + threadIdx.x; i < E; i += stride)
    atomicAdd(&lh[dst[i] >> 7], 1);
  __syncthreads();
  for (int i = threadIdx.x; i < NB; i += blockDim.x)
    if (lh[i]) atomicAdd(&bhist[i], lh[i]);
}

__global__ void p_scan(const int* __restrict__ bhist, int* __restrict__ boff,
                       int* __restrict__ bcur, int* __restrict__ ptr,
                       int NB, int N, int E){
  __shared__ int ls[512];
  int t = threadIdx.x;
  int v = (t < NB) ? bhist[t] : 0;
  ls[t] = v; __syncthreads();
  for (int o = 1; o < 512; o <<= 1){
    int y = (t >= o) ? ls[t-o] : 0;
    __syncthreads();
    ls[t] += y;
    __syncthreads();
  }
  int ex = ls[t] - v;
  if (t < NB){ boff[t] = ex; bcur[t] = ex; }
  if (t == 0){ boff[NB] = E; ptr[N] = E; }
}

#define BIN_CHUNK 8192
__global__ void p_bin(const int* __restrict__ src, const int* __restrict__ dst,
                      int* __restrict__ bcur, unsigned int* __restrict__ recs,
                      int E, int NB){
  __shared__ int lh[512];
  __shared__ int lbase[512];
  int c0 = blockIdx.x * BIN_CHUNK;
  int cnt = min(BIN_CHUNK, E - c0);
  if (cnt <= 0) return;
  int t = threadIdx.x;
  for (int i = t; i < NB; i += blockDim.x) lh[i] = 0;
  __syncthreads();
  for (int i = t; i < cnt; i += blockDim.x)
    atomicAdd(&lh[dst[c0+i] >> 7], 1);
  __syncthreads();
  for (int i = t; i < NB; i += blockDim.x){
    int c = lh[i];
    lbase[i] = (c > 0) ? atomicAdd(&bcur[i], c) : 0;
    lh[i] = 0;
  }
  __syncthreads();
  for (int i = t; i < cnt; i += blockDim.x){
    int d = dst[c0+i];
    int b = d >> 7;
    int p = atomicAdd(&lh[b], 1);
    recs[lbase[b] + p] = ((unsigned int)src[c0+i] << 7) | (unsigned int)(d & 127);
  }
}

__global__ void p_csr(const unsigned int* __restrict__ recs, const int* __restrict__ boff,
                      int* __restrict__ ptr, int* __restrict__ srcs, int N){
  int b = blockIdx.x;
  int r0 = boff[b], r1 = boff[b+1];
  __shared__ int lh[128];
  int t = threadIdx.x;
  if (t < 128) lh[t] = 0;
  __syncthreads();
  for (int i = r0 + t; i < r1; i += 256)
    atomicAdd(&lh[recs[i] & 127u], 1);
  __syncthreads();
  int mycnt = (t < 128) ? lh[t] : 0;
  for (int o = 1; o < 128; o <<= 1){
    int y = (t < 128 && t >= o) ? lh[t-o] : 0;
    __syncthreads();
    if (t < 128) lh[t] += y;
    __syncthreads();
  }
  if (t < 128){
    int excl = lh[t] - mycnt;
    int node = b*128 + t;
    if (node < N) ptr[node] = r0 + excl;
    lh[t] = excl;
  }
  __syncthreads();
  for (int i = r0 + t; i < r1; i += 256){
    unsigned int rec = recs[i];
    int j = rec & 127u;
    int p = atomicAdd(&lh[j], 1);
    srcs[r0 + p] = (int)(rec >> 7);
  }
}

// ---- MFMA GEMM: Y[N x NG*64] = X[N x 64] @ W, mfma_f32_16x16x32_bf16.
// W staged to LDS as pre-swizzled bf16 B-frags; each wave computes strips of
// 16 rows over ALL col tiles. NG=3 adds skipW tiles. (R11: this replaced the
// allocator-bound fp32-FMA GEMM, 85us -> off the profile.)
template<int NG>
__global__ void k_gemm(const float* __restrict__ X, const float* __restrict__ Wm,
                       const float* __restrict__ Wsk, const float* __restrict__ att_s,
                       const float* __restrict__ att_d, unsigned short* __restrict__ Hout,
                       float* __restrict__ skv, float* __restrict__ a_s,
                       float* __restrict__ a_d, int N){
  constexpr int NT = NG*4;                    // 16-col tiles
  __shared__ unsigned short Bl[NT*2*64*8];    // [tile][khalf][lane][8] bf16
  int t = threadIdx.x;
  const int TOT = 64 * NG * 64;               // k * cols
  for (int e = t; e < TOT; e += 256){
    int k = e / (NG*64), c = e % (NG*64);
    float w = (c < 128) ? Wm[(size_t)k*128 + c] : Wsk[(size_t)k*64 + (c-128)];
    int ct = c >> 4;
    int h = k >> 5, kk = k & 31;
    int e2 = ((kk >> 4) << 2) | (kk & 3);
    int l  = (c & 15) | (((kk >> 2) & 3) << 4);
    Bl[(((ct*2 + h)*64) + l)*8 + e2] = f2bf(w);
  }
  __syncthreads();

  int lane = t & 63, wav = t >> 6;
  int m = lane & 15, g = lane >> 4;
  float asv[8], adv[8];
  #pragma unroll
  for (int ct = 0; ct < 8; ct++){ asv[ct] = att_s[ct*16 + m]; adv[ct] = att_d[ct*16 + m]; }

  #pragma unroll
  for (int it = 0; it < 2; it++){
    int rbase = blockIdx.x*128 + it*64 + wav*16;
    if (rbase >= N) break;
    int r = min(rbase + m, N-1);
    const float* xr = X + (size_t)r*64;
    float4 u0 = *(const float4*)(xr + g*4);
    float4 u1 = *(const float4*)(xr + 16 + g*4);
    float4 u2 = *(const float4*)(xr + 32 + g*4);
    float4 u3 = *(const float4*)(xr + 48 + g*4);
    bf16x8 a0, a1;
    a0[0]=(short)f2bf(u0.x); a0[1]=(short)f2bf(u0.y); a0[2]=(short)f2bf(u0.z); a0[3]=(short)f2bf(u0.w);
    a0[4]=(short)f2bf(u1.x); a0[5]=(short)f2bf(u1.y); a0[6]=(short)f2bf(u1.z); a0[7]=(short)f2bf(u1.w);
    a1[0]=(short)f2bf(u2.x); a1[1]=(short)f2bf(u2.y); a1[2]=(short)f2bf(u2.z); a1[3]=(short)f2bf(u2.w);
    a1[4]=(short)f2bf(u3.x); a1[5]=(short)f2bf(u3.y); a1[6]=(short)f2bf(u3.z); a1[7]=(short)f2bf(u3.w);

    f32x4 acc[NT];
    #pragma unroll
    for (int ct = 0; ct < NT; ct++) acc[ct] = (f32x4){0.f,0.f,0.f,0.f};
    #pragma unroll
    for (int ct = 0; ct < NT; ct++){
      bf16x8 b0 = *(const bf16x8*)&Bl[((ct*2+0)*64 + lane)*8];
      bf16x8 b1 = *(const bf16x8*)&Bl[((ct*2+1)*64 + lane)*8];
      acc[ct] = __builtin_amdgcn_mfma_f32_16x16x32_bf16(a0, b0, acc[ct], 0, 0, 0);
      acc[ct] = __builtin_amdgcn_mfma_f32_16x16x32_bf16(a1, b1, acc[ct], 0, 0, 0);
    }

    float ds0[4]={0,0,0,0}, dd0[4]={0,0,0,0}, ds1[4]={0,0,0,0}, dd1[4]={0,0,0,0};
    #pragma unroll
    for (int ct = 0; ct < 8; ct++){
      #pragma unroll
      for (int q = 0; q < 4; q++){
        float v = acc[ct][q];
        if (ct < 4){ ds0[q] = fmaf(v, asv[ct], ds0[q]); dd0[q] = fmaf(v, adv[ct], dd0[q]); }
        else       { ds1[q] = fmaf(v, asv[ct], ds1[q]); dd1[q] = fmaf(v, adv[ct], dd1[q]); }
      }
    }
    #pragma unroll
    for (int off = 1; off < 16; off <<= 1){
      #pragma unroll
      for (int q = 0; q < 4; q++){
        ds0[q] += __shfl_xor(ds0[q], off); dd0[q] += __shfl_xor(dd0[q], off);
        ds1[q] += __shfl_xor(ds1[q], off); dd1[q] += __shfl_xor(dd1[q], off);
      }
    }
    if (m == 0){
      #pragma unroll
      for (int q = 0; q < 4; q++){
        int rr = rbase + g*4 + q;
        if (rr < N){
          float2 s2; s2.x = ds0[q]; s2.y = ds1[q]; ((float2*)a_s)[rr] = s2;
          float2 d2; d2.x = dd0[q]; d2.y = dd1[q]; ((float2*)a_d)[rr] = d2;
        }
      }
    }
    #pragma unroll
    for (int ct = 0; ct < 8; ct++){
      #pragma unroll
      for (int q = 0; q < 4; q++){
        int rr = rbase + g*4 + q;
        if (rr < N) Hout[(size_t)rr*128 + ct*16 + m] = f2bf(acc[ct][q]);
      }
    }
    if (NG >= 3){
      #pragma unroll
      for (int ct = 8; ct < NT; ct++){
        #pragma unroll
        for (int q = 0; q < 4; q++){
          int rr = rbase + g*4 + q;
          if (rr < N) skv[(size_t)rr*64 + (ct-8)*16 + m] = acc[ct][q];
        }
      }
    }
  }
}

// ---- GAT aggregation: one wave per node, single pass.
// R11 post-mortem: VALUBusy 55% from ~10 VALU/edge (64-bit addr math, float4
// unpack, cndmask). New inner loop: uniform LDS byte-offset + [2][64] weight
// LDS (lane>>5 pick, 2-addr broadcast = free), 32-bit saddr loads ->
// ~5 VALU/edge (or, 2 unpack, 2 fma).
__global__ void k_agg(const unsigned short* __restrict__ Hp, const float* __restrict__ a_s,
                      const float* __restrict__ a_d, const int* __restrict__ ptr,
                      const int* __restrict__ srcs, const float* __restrict__ bias,
                      float* __restrict__ out, int N){
  __shared__ unsigned int sbuf[4][64];
  __shared__ float wbuf[4][2][64];
  int tid = threadIdx.x;
  int wv = tid >> 6;
  int wid = (blockIdx.x*blockDim.x + tid) >> 6;
  int lane = tid & 63;
  if (wid >= N) return;
  int n = wid;
  const char* HB = (const char*)Hp;            // rows of 256 B
  const float2* AS2 = (const float2*)a_s;
  float2 adv = ((const float2*)a_d)[n];
  float2 asv = AS2[n];
  int e0 = ptr[n], e1 = ptr[n+1];
  float w0 = __expf(lrelu(asv.x + adv.x));
  float w1 = __expf(lrelu(asv.y + adv.y));
  unsigned lane4 = (unsigned)lane << 2;
  unsigned int hw = *(const unsigned int*)(HB + (((unsigned)n << 8) | lane4));
  float wsel = (lane < 32) ? w0 : w1;
  float acc0 = __uint_as_float(hw << 16) * wsel;
  float acc1 = __uint_as_float(hw & 0xffff0000u) * wsel;
  float d0 = 0.f, d1 = 0.f;
  int hsel = lane >> 5;
  for (int base = e0; base < e1; base += 64){
    int i = base + lane;
    float e_0 = 0.f, e_1 = 0.f; unsigned sv = 0;
    if (i < e1){
      sv = (unsigned)srcs[i];
      float2 av = AS2[sv];
      e_0 = __expf(lrelu(av.x + adv.x));
      e_1 = __expf(lrelu(av.y + adv.y));
    }
    d0 += e_0; d1 += e_1;
    sbuf[wv][lane] = sv << 8;                 // row byte offset
    wbuf[wv][0][lane] = e_0;
    wbuf[wv][1][lane] = e_1;
    int cnt = min(64, e1 - base);
    #pragma unroll 8
    for (int j = 0; j < cnt; j++){
      unsigned off = sbuf[wv][j];             // wave-uniform broadcast
      float wss = wbuf[wv][hsel][j];          // 2-address broadcast (free)
      unsigned int hj = *(const unsigned int*)(HB + (off | lane4));
      acc0 = fmaf(__uint_as_float(hj << 16),         wss, acc0);
      acc1 = fmaf(__uint_as_float(hj & 0xffff0000u), wss, acc1);
    }
  }
  #pragma unroll
  for (int o=32;o>0;o>>=1){ d0 += __shfl_xor(d0,o); d1 += __shfl_xor(d1,o); }
  d0 += w0; d1 += w1;
  float dsel = (lane < 32) ? d0 : d1;
  acc0 /= dsel; acc1 /= dsel;
  float o0 = 0.5f*(acc0 + __shfl_xor(acc0, 32));
  float o1 = 0.5f*(acc1 + __shfl_xor(acc1, 32));
  if (lane < 32){
    float2 res; res.x = o0 + bias[2*lane]; res.y = o1 + bias[2*lane+1];
    ((float2*)out)[(size_t)n*32 + lane] = res;
  }
}

// ---- BN stats: per-channel sum / sumsq ----
__global__ void k_bnstats(const float* __restrict__ X, float* __restrict__ part, int N){
  int t = threadIdx.x; int c = t & 63; int sub = t >> 6;
  float s = 0.f, s2 = 0.f;
  for (int r = blockIdx.x*4 + sub; r < N; r += gridDim.x*4){
    float v = X[(size_t)r*64 + c];
    s += v; s2 = fmaf(v, v, s2);
  }
  __shared__ float ls[256], lq[256];
  ls[t] = s; lq[t] = s2; __syncthreads();
  if (t < 64){
    s  = ls[t] + ls[t+64] + ls[t+128] + ls[t+192];
    s2 = lq[t] + lq[t+64] + lq[t+128] + lq[t+192];
    atomicAdd(&part[t], s);
    atomicAdd(&part[64+t], s2);
  }
}

// ---- hmid = gelu(bn(g1) + skip + skipb); bn params derived inline (folds
// the old k_bnfinal kernel away) ----
__global__ void k_fuse1(const float* __restrict__ g1, const float* __restrict__ part,
                        const float* __restrict__ gamma, const float* __restrict__ beta,
                        const float* __restrict__ skip, const float* __restrict__ skipb,
                        float* __restrict__ hmid, int total, float invN){
  int i = blockIdx.x*blockDim.x + threadIdx.x;
  if (i < total){
    int c = i & 63;
    float mu  = part[c] * invN;
    float var = fmaxf(part[64+c] * invN - mu*mu, 0.f);
    float sc  = gamma[c] * rsqrtf(var + 1e-5f);
    float sh  = beta[c] - mu*sc;
    float v = fmaf(g1[i], sc, sh) + skip[i] + skipb[c];
    hmid[i] = gelu_tanh(v);
  }
}

// ---- final: gelu(bn(g2)+hmid), pooled sums per batch; bn derived inline ----
__global__ void k_fusepool(const float* __restrict__ g2, const float* __restrict__ part,
                           const float* __restrict__ gamma, const float* __restrict__ beta,
                           const float* __restrict__ hmid, const int* __restrict__ batch,
                           float* __restrict__ pool, float* __restrict__ cnt, int N, float invN){
  int t = threadIdx.x; int c = t & 63; int sub = t >> 6;
  int r0 = blockIdx.x*64;
  float mu  = part[c] * invN;
  float var = fmaxf(part[64+c] * invN - mu*mu, 0.f);
  float scale = gamma[c] * rsqrtf(var + 1e-5f);
  float shift = beta[c] - mu*scale;
  float acc = 0.f, ca = 0.f; int curb = -1;
  for (int r = r0 + sub; r < N && r < r0 + 64; r += 4){
    int b = batch[r];
    if (b != curb){
      if (curb >= 0){
        atomicAdd(&pool[curb*64 + c], acc);
        if (c == 0) atomicAdd(&cnt[curb], ca);
      }
      acc = 0.f; ca = 0.f; curb = b;
    }
    float v = gelu_tanh(fmaf(g2[(size_t)r*64 + c], scale, shift) + hmid[(size_t)r*64 + c]);
    acc += v; ca += 1.f;
  }
  if (curb >= 0){
    atomicAdd(&pool[curb*64 + c], acc);
    if (c == 0) atomicAdd(&cnt[curb], ca);
  }
}

__global__ void k_out(const float* __restrict__ pool, const float* __restrict__ cnt,
                      float* __restrict__ out, int M){
  int i = blockIdx.x*blockDim.x + threadIdx.x;
  if (i < M) out[i] = pool[i] / fmaxf(cnt[i>>6], 1.f);
}

extern "C" void kernel_launch(void* const* d_in, const int* in_sizes, int n_in,
                              void* d_out, int out_size, void* d_ws, size_t ws_size,
                              hipStream_t stream) {
  const float* x     = (const float*)d_in[0];
  const int*   ei    = (const int*)  d_in[1];
  const int*   batch = (const int*)  d_in[2];
  const float* W1    = (const float*)d_in[3];
  const float* as1   = (const float*)d_in[4];
  const float* ad1   = (const float*)d_in[5];
  const float* b1    = (const float*)d_in[6];
  const float* skW   = (const float*)d_in[7];
  const float* skb   = (const float*)d_in[8];
  const float* gm1   = (const float*)d_in[9];
  const float* bt1   = (const float*)d_in[10];
  const float* W2    = (const float*)d_in[11];
  const float* as2   = (const float*)d_in[12];
  const float* ad2   = (const float*)d_in[13];
  const float* b2    = (const float*)d_in[14];
  const float* gm2   = (const float*)d_in[15];
  const float* bt2   = (const float*)d_in[16];

  int N = in_sizes[2];
  int E = in_sizes[1] / 2;
  const int* esrc = ei;
  const int* edst = ei + E;
  int NB = (N + 127) >> 7;          // 128-node buckets
  float invN = 1.0f / (float)N;

  char* wp = (char*)d_ws;
  size_t off = 0;
  auto alloc = [&](size_t bytes)->void*{
    off = (off + 255) & ~(size_t)255;
    void* p = wp + off;
    off += bytes;
    return p;
  };
  int*   ptr   = (int*)  alloc((size_t)(N+1)*4);
  int*   srcs  = (int*)  alloc((size_t)E*4);
  unsigned int* recs = (unsigned int*)alloc((size_t)E*4);
  int*   bhist = (int*)  alloc(512*4);
  int*   boff  = (int*)  alloc(520*4);
  int*   bcur  = (int*)  alloc(512*4);
  unsigned short* hpack = (unsigned short*)alloc((size_t)N*128*2);  // bf16 H
  float* a_s  = (float*)alloc((size_t)N*2*4);
  float* a_d  = (float*)alloc((size_t)N*2*4);
  float* gout = (float*)alloc((size_t)N*64*4);   // GAT raw output (both layers)
  float* skv  = (float*)alloc((size_t)N*64*4);   // x @ skipW
  float* hmid = (float*)alloc((size_t)N*64*4);   // layer-1 final output
  float* zz   = (float*)alloc((size_t)(128+128+4096+64)*4); // zero zone
  float* part1 = zz;
  float* part2 = zz + 128;
  float* pool  = zz + 256;
  float* cnt   = zz + 256 + 4096;

  hipMemsetAsync(bhist, 0, 512*4, stream);
  hipMemsetAsync(zz, 0, (size_t)(128+128+4096+64)*4, stream);

  int gg = (N + 127) / 128;

  // CSR build (bucket sort)
  p_hist<<<512, 256, 0, stream>>>(edst, bhist, E, NB);
  p_scan<<<1, 512, 0, stream>>>(bhist, boff, bcur, ptr, NB, N, E);
  p_bin<<<(E + BIN_CHUNK - 1)/BIN_CHUNK, 256, 0, stream>>>(esrc, edst, bcur, recs, E, NB);
  p_csr<<<NB, 256, 0, stream>>>(recs, boff, ptr, srcs, N);

  // layer 1 (W1 + skip + att fused, MFMA)
  k_gemm<3><<<gg, 256, 0, stream>>>(x, W1, skW, as1, ad1, hpack, skv, a_s, a_d, N);
  k_agg<<<(N+3)/4, 256, 0, stream>>>(hpack, a_s, a_d, ptr, srcs, b1, gout, N);
  k_bnstats<<<256, 256, 0, stream>>>(gout, part1, N);
  k_fuse1<<<(N*64 + 255)/256, 256, 0, stream>>>(gout, part1, gm1, bt1, skv, skb, hmid, N*64, invN);

  // layer 2
  k_gemm<2><<<gg, 256, 0, stream>>>(hmid, W2, nullptr, as2, ad2, hpack, nullptr, a_s, a_d, N);
  k_agg<<<(N+3)/4, 256, 0, stream>>>(hpack, a_s, a_d, ptr, srcs, b2, gout, N);
  k_bnstats<<<256, 256, 0, stream>>>(gout, part2, N);

  // fuse + pool (bn2 derived inline)
  k_fusepool<<<(N+63)/64, 256, 0, stream>>>(gout, part2, gm2, bt2, hmid, batch, pool, cnt, N, invN);
  k_out<<<(out_size + 255)/256, 256, 0, stream>>>(pool, cnt, (float*)d_out, out_size);
}